// Round 12
// baseline (14473.537 us; speedup 1.0000x reference)
//
#include <hip/hip_runtime.h>
#include <stdint.h>

#define T_STEPS 4096
#define BATCH 32
#define HID 512
#define GROUPS 8            // blocks per batch
#define BLK_THREADS 512     // 8 waves (R20 best structure)
#define NBLOCKS 256
#define SLOT_DW (BATCH * GROUPS * 64)  // dwords per parity slot (16384 = 64 KB)

typedef _Float16 h2_t __attribute__((ext_vector_type(2)));
typedef uint32_t u32x4 __attribute__((ext_vector_type(4)));
typedef uint32_t u32x8 __attribute__((ext_vector_type(8)));

__device__ inline uint32_t pack_h2(float a, float b) {
  h2_t v;
  v.x = (_Float16)a;
  v.y = (_Float16)b;
  return __builtin_bit_cast(uint32_t, v);
}

__device__ inline float fdot2(uint32_t a, uint32_t b, float c) {
  return __builtin_amdgcn_fdot2(__builtin_bit_cast(h2_t, a),
                                __builtin_bit_cast(h2_t, b), c, false);
}

__device__ inline uint64_t uni64(const void* p) {
  uint32_t lo = __builtin_amdgcn_readfirstlane((uint32_t)(uintptr_t)p);
  uint32_t hi = __builtin_amdgcn_readfirstlane((uint32_t)((uintptr_t)p >> 32));
  return ((uint64_t)hi << 32) | lo;
}

__device__ inline void kinv() {
  asm volatile("s_dcache_inv" ::: "memory");
}

// R11's fused poll+fetch (transport of every best round): 8 scalar loads
// back-to-back, ONE lgkmcnt(0) — 36 useful dwords (32 data + 4 in-line tags).
__device__ inline void sload_rec(uint64_t p, u32x8* d0, u32x8* d1,
                                 u32x8* d2, u32x8* d3,
                                 uint32_t* t0, uint32_t* t1,
                                 uint32_t* t2, uint32_t* t3) {
  asm volatile("s_load_dwordx8 %0, %8, 0x0\n\t"
               "s_load_dword %4, %8, 0x20\n\t"
               "s_load_dwordx8 %1, %8, 0x40\n\t"
               "s_load_dword %5, %8, 0x60\n\t"
               "s_load_dwordx8 %2, %8, 0x80\n\t"
               "s_load_dword %6, %8, 0xa0\n\t"
               "s_load_dwordx8 %3, %8, 0xc0\n\t"
               "s_load_dword %7, %8, 0xe0\n\t"
               "s_waitcnt lgkmcnt(0)"
               : "=&s"(*d0), "=&s"(*d1), "=&s"(*d2), "=&s"(*d3),
                 "=&s"(*t0), "=&s"(*t1), "=&s"(*t2), "=&s"(*t3)
               : "s"(p) : "memory");
}

__device__ inline float sigf(float x) { return 1.0f / (1.0f + __expf(-x)); }
__device__ inline float tanh_fast(float x) {
  float a = fabsf(x);
  float e = __expf(-2.0f * a);
  float r = (1.0f - e) / (1.0f + e);
  return copysignf(r, x);
}

// Round 21: wave-0 serial-tail trim. R20 measured == R19 (13.97 vs 13.98 ms)
// -> fan-in width / spin policy / ILP all innocent. Remaining untouched
// critical-path pieces, all on wave 0:
//  1. wave 0 polled its OWN block's record through L2 — now it matvecs from
//     a 4-deep LDS stash of its own packed h (broadcast ds_read_b128; no
//     kinv / s_load / L2 RT for slice g).
//  2. the 6-stage shfl_xor y-reduction ran AFTER publish, delaying wave 0's
//     next-step arrival — now y(t-1) is computed from the LDS stash DURING
//     wave 0's arrive-spin window (work where idle was).
//  3. blin was only loaded by tid<64 but used by all threads in the drain
//     (g==0 outputs got blin=0 for 15/16 of rows) — fixed; absmax margin.
// Waves 1-7: byte-identical R20 poll/matvec/arrive path.
__global__ __launch_bounds__(BLK_THREADS)
void lstm_w8t(const float* __restrict__ x0,
              const float* __restrict__ W_ih,
              const float* __restrict__ W_hh,
              const float* __restrict__ b_ih,
              const float* __restrict__ b_hh,
              const float* __restrict__ W_lin,
              const float* __restrict__ b_lin,
              float* __restrict__ y,
              uint32_t* __restrict__ h_ex,   // [2][BATCH][GROUPS][64]
              int* __restrict__ claim)       // [8][16] per-XCD claim ctrs
{
  __shared__ float x0_lds[T_STEPS];     // 16 KB
  __shared__ float ylds[T_STEPS];       // 16 KB
  __shared__ float gacc[2][256];        // parity-buffered gate accumulators
  __shared__ __align__(16) uint32_t h_self[4][32];  // wave-0 local h ring
  __shared__ int arrive[2];             // parity arrival counters
  __shared__ int s_bg;

  const int tid = threadIdx.x;

  // ---- claim a (batch, group) slot on THIS block's physical XCD ----
  if (tid == 0) {
    uint32_t xcc;
    asm volatile("s_getreg_b32 %0, hwreg(HW_REG_XCC_ID)" : "=s"(xcc));
    xcc &= 7;
    int slot = atomicAdd(claim + xcc * 16, 1);   // one-time
    s_bg = (slot < 32) ? (int)(((4 * xcc + (slot >> 3)) << 3) | (slot & 7))
                       : -1;
  }
  __syncthreads();
  if (s_bg < 0) return;                  // surplus block
  const int b  = s_bg >> 3;              // batch (same XCD for all 8 groups)
  const int g  = s_bg & 7;               // group within batch
  const int u0 = g * 64;                 // first hidden unit owned
  const int wv = tid >> 6;               // wave 0..7
  const int cs = (g + wv) & 7;           // col-slice; wave 0 -> OWN slice g
  const int l  = tid & 63;

  // ---- one-time: W_hh slice -> packed f16x2 -> VGPRs ----
  // Wave handles acc rows j = 64a + l (a = gate 0..3), cols 64cs..64cs+63.
  uint32_t w[4][32];
#pragma unroll
  for (int a = 0; a < 4; ++a) {
    const int R = a * HID + u0 + l;                    // gate*512 + unit
    const float2* p = (const float2*)(W_hh + (size_t)R * HID + 64 * cs);
#pragma unroll
    for (int k = 0; k < 32; ++k) {
      float2 q = p[k];
      w[a][k] = pack_h2(q.x, q.y);
    }
  }
  // ---- one-time: x0 column, y partials, gacc, arrive, h ring ----
  for (int i = tid; i < T_STEPS; i += BLK_THREADS) {
    x0_lds[i] = x0[i * BATCH + b];
    ylds[i] = 0.f;
  }
  if (tid < 256) { gacc[0][tid] = 0.f; gacc[1][tid] = 0.f; }
  if (tid < 128) ((uint32_t*)h_self)[tid] = 0;    // h_0 = 0
  if (tid < 2) arrive[tid] = 0;

  // ---- activation-lane constants ----
  float c_state = 0.f;
  float wih_[4] = {0.f, 0.f, 0.f, 0.f}, bs_[4] = {0.f, 0.f, 0.f, 0.f};
  float wlin_u = 0.f;
  const float blin = b_lin[0];          // ALL threads (drain uses it)
  if (tid < 64) {
#pragma unroll
    for (int j = 0; j < 4; ++j) {
      int R = j * HID + u0 + tid;
      wih_[j] = W_ih[R];
      bs_[j] = b_ih[R] + b_hh[R];
    }
    wlin_u = W_lin[u0 + tid];
  }

  // ---- wave-uniform SGPR addresses (tagged-line record layout) ----
  uint32_t* hb = h_ex + (size_t)b * (GROUPS * 64);
  const uint64_t dpu[2] = { uni64(hb + 64 * cs),
                            uni64(hb + SLOT_DW + 64 * cs) };
  uint32_t* pub01[2] = { hb + 64 * g, hb + SLOT_DW + 64 * g };

  __syncthreads();

  int dead = 0;
  for (int t = 0; t < T_STEPS; ++t) {
    const int sl = t & 1, ns = sl ^ 1;

    if (wv != 0) {
      // ======== waves 1-7: R20 path, byte-identical ========
      u32x8 D0, D1, D2, D3;
      uint32_t tg0, tg1, tg2, tg3;
      {
        const uint32_t want = (uint32_t)t;
        int guard = 0;
        for (;;) {
          kinv();
          sload_rec(dpu[sl], &D0, &D1, &D2, &D3, &tg0, &tg1, &tg2, &tg3);
          if ((tg0 == want) & (tg1 == want) &
              (tg2 == want) & (tg3 == want)) break;
          if (dead || ++guard > (1 << 14)) { dead = 1; break; }  // anti-hang
        }
      }
      __builtin_amdgcn_s_setprio(1);
      float ae0 = 0.f, ao0 = 0.f, ae1 = 0.f, ao1 = 0.f;
      float ae2 = 0.f, ao2 = 0.f, ae3 = 0.f, ao3 = 0.f;
#pragma unroll
      for (int k = 0; k < 8; k += 2) {
        ae0 = fdot2(w[0][k], D0[k], ae0);      ao0 = fdot2(w[0][k + 1], D0[k + 1], ao0);
        ae1 = fdot2(w[1][k], D0[k], ae1);      ao1 = fdot2(w[1][k + 1], D0[k + 1], ao1);
        ae2 = fdot2(w[2][k], D0[k], ae2);      ao2 = fdot2(w[2][k + 1], D0[k + 1], ao2);
        ae3 = fdot2(w[3][k], D0[k], ae3);      ao3 = fdot2(w[3][k + 1], D0[k + 1], ao3);
        ae0 = fdot2(w[0][8 + k], D1[k], ae0);  ao0 = fdot2(w[0][9 + k], D1[k + 1], ao0);
        ae1 = fdot2(w[1][8 + k], D1[k], ae1);  ao1 = fdot2(w[1][9 + k], D1[k + 1], ao1);
        ae2 = fdot2(w[2][8 + k], D1[k], ae2);  ao2 = fdot2(w[2][9 + k], D1[k + 1], ao2);
        ae3 = fdot2(w[3][8 + k], D1[k], ae3);  ao3 = fdot2(w[3][9 + k], D1[k + 1], ao3);
        ae0 = fdot2(w[0][16 + k], D2[k], ae0); ao0 = fdot2(w[0][17 + k], D2[k + 1], ao0);
        ae1 = fdot2(w[1][16 + k], D2[k], ae1); ao1 = fdot2(w[1][17 + k], D2[k + 1], ao1);
        ae2 = fdot2(w[2][16 + k], D2[k], ae2); ao2 = fdot2(w[2][17 + k], D2[k + 1], ao2);
        ae3 = fdot2(w[3][16 + k], D2[k], ae3); ao3 = fdot2(w[3][17 + k], D2[k + 1], ao3);
        ae0 = fdot2(w[0][24 + k], D3[k], ae0); ao0 = fdot2(w[0][25 + k], D3[k + 1], ao0);
        ae1 = fdot2(w[1][24 + k], D3[k], ae1); ao1 = fdot2(w[1][25 + k], D3[k + 1], ao1);
        ae2 = fdot2(w[2][24 + k], D3[k], ae2); ao2 = fdot2(w[2][25 + k], D3[k + 1], ao2);
        ae3 = fdot2(w[3][24 + k], D3[k], ae3); ao3 = fdot2(w[3][25 + k], D3[k + 1], ao3);
      }
      atomicAdd(&gacc[sl][l],       ae0 + ao0);
      atomicAdd(&gacc[sl][64 + l],  ae1 + ao1);
      atomicAdd(&gacc[sl][128 + l], ae2 + ao2);
      atomicAdd(&gacc[sl][192 + l], ae3 + ao3);
      asm volatile("" ::: "memory");
      if (l == 0) atomicAdd(&arrive[sl], 1);
      __builtin_amdgcn_s_setprio(0);
      continue;                          // straight to poll t+1
    }

    // ======== wave 0: local-h matvec, act, publish ========
    __builtin_amdgcn_s_setprio(1);
    {
      // matvec from own stash (broadcast ds_read_b128; no poll, no L2)
      const u32x4* Vb = (const u32x4*)h_self[t & 3];
      float ae0 = 0.f, ao0 = 0.f, ae1 = 0.f, ao1 = 0.f;
      float ae2 = 0.f, ao2 = 0.f, ae3 = 0.f, ao3 = 0.f;
#pragma unroll
      for (int q = 0; q < 8; ++q) {
        u32x4 V = Vb[q];
#pragma unroll
        for (int j = 0; j < 4; j += 2) {
          const int k = 4 * q + j;
          ae0 = fdot2(w[0][k], V[j], ae0);  ao0 = fdot2(w[0][k + 1], V[j + 1], ao0);
          ae1 = fdot2(w[1][k], V[j], ae1);  ao1 = fdot2(w[1][k + 1], V[j + 1], ao1);
          ae2 = fdot2(w[2][k], V[j], ae2);  ao2 = fdot2(w[2][k + 1], V[j + 1], ao2);
          ae3 = fdot2(w[3][k], V[j], ae3);  ao3 = fdot2(w[3][k + 1], V[j + 1], ao3);
        }
      }
      atomicAdd(&gacc[sl][l],       ae0 + ao0);
      atomicAdd(&gacc[sl][64 + l],  ae1 + ao1);
      atomicAdd(&gacc[sl][128 + l], ae2 + ao2);
      atomicAdd(&gacc[sl][192 + l], ae3 + ao3);
      asm volatile("" ::: "memory");
      if (l == 0) atomicAdd(&arrive[sl], 1);
    }

    // deferred y(t-1) — fills the arrive-wait window (off critical path)
    if (t > 0) {
      uint16_t hu = ((volatile uint16_t*)h_self[t & 3])[l];
      float p = wlin_u * (float)__builtin_bit_cast(_Float16, hu);
#pragma unroll
      for (int m = 32; m >= 1; m >>= 1) p += __shfl_xor(p, m, 64);
      if (l == 0) ylds[t - 1] = p;
    }

    // fan-in: wait for waves 1-7 (+ self)
    {
      int guard = 0;
      while (((volatile int*)arrive)[sl] < 8) {
        if (++guard > (1 << 20)) break;            // anti-hang
      }
    }
    asm volatile("" ::: "memory");
    arrive[sl] = 0;                      // reset for t+2 (tag chain gates)

    // activation
    const float xv = x0_lds[t];
    float gi = gacc[sl][l]       + xv * wih_[0] + bs_[0];
    float gf = gacc[sl][l + 64]  + xv * wih_[1] + bs_[1];
    float gg = gacc[sl][l + 128] + xv * wih_[2] + bs_[2];
    float go = gacc[sl][l + 192] + xv * wih_[3] + bs_[3];
    float si = sigf(gi), sf = sigf(gf), tg_ = tanh_fast(gg), so = sigf(go);
    c_state = sf * c_state + si * tg_;
    float h = so * tanh_fast(c_state);

    // remote publish FIRST: 36-lane predicated store of 4 tagged lines
    float hn = __shfl_down(h, 1, 64);
    uint32_t pk = pack_h2(h, hn);
    {
      uint32_t val = 0;
      int doff = 0;
      bool act = false;
      if ((l & 1) == 0) {
        int j = l >> 1;
        val = pk;
        doff = ((j >> 3) << 4) + (j & 7);
        act = true;
      } else if (l < 8) {
        int L = (l - 1) >> 1;
        val = (uint32_t)(t + 1);
        doff = (L << 4) + 8;
        act = true;
      }
      if (act) pub01[ns][doff] = val;
    }
    // stash h_{t+1} locally (4-deep ring; read back at t+1 and for y)
    if ((l & 1) == 0) h_self[(t + 1) & 3][l >> 1] = pk;
    // recycle gacc[sl] for t+2
    gacc[sl][l] = 0.f;
    gacc[sl][l + 64] = 0.f;
    gacc[sl][l + 128] = 0.f;
    gacc[sl][l + 192] = 0.f;
    __builtin_amdgcn_s_setprio(0);
  }

  // final y: ylds[T-1] from h_T (stashed at t = T-1 into ring slot 0)
  if (wv == 0) {
    uint16_t hu = ((volatile uint16_t*)h_self[T_STEPS & 3])[l];
    float p = wlin_u * (float)__builtin_bit_cast(_Float16, hu);
#pragma unroll
    for (int m = 32; m >= 1; m >>= 1) p += __shfl_xor(p, m, 64);
    if (l == 0) ylds[T_STEPS - 1] = p;
  }

  // ---- drain: block partials -> global y (g==0 adds bias + residual) ----
  __syncthreads();
  for (int i = tid; i < T_STEPS; i += BLK_THREADS) {
    float val = ylds[i];
    if (g == 0) val += blin + x0_lds[i];
    unsafeAtomicAdd(&y[i * BATCH + b], val);
  }
}

extern "C" void kernel_launch(void* const* d_in, const int* in_sizes, int n_in,
                              void* d_out, int out_size, void* d_ws, size_t ws_size,
                              hipStream_t stream) {
  const float* x0    = (const float*)d_in[0];
  const float* W_ih  = (const float*)d_in[1];
  const float* W_hh  = (const float*)d_in[2];
  const float* b_ih  = (const float*)d_in[3];
  const float* b_hh  = (const float*)d_in[4];
  const float* W_lin = (const float*)d_in[5];
  const float* b_lin = (const float*)d_in[6];
  float* y = (float*)d_out;

  uint32_t* h_ex = (uint32_t*)d_ws;                    // 2 x 64 KB slots
  int* claim     = (int*)(h_ex + 2 * SLOT_DW);         // 512 B
  const size_t init_bytes = (size_t)2 * SLOT_DW * sizeof(uint32_t)
                            + 8 * 16 * sizeof(int);

  // memset 0: slot-0 tags = 0 with h = 0 (== "h_0 available"), claim = 0
  (void)hipMemsetAsync(d_ws, 0, init_bytes, stream);
  (void)hipMemsetAsync(d_out, 0, (size_t)out_size * sizeof(float), stream);

  hipLaunchKernelGGL(lstm_w8t, dim3(NBLOCKS), dim3(BLK_THREADS), 0, stream,
                     x0, W_ih, W_hh, b_ih, b_hh, W_lin, b_lin, y, h_ex, claim);
}

// Round 13
// 14123.579 us; speedup vs baseline: 1.0248x; 1.0248x over previous
//
#include <hip/hip_runtime.h>
#include <stdint.h>

#define T_STEPS 4096
#define BATCH 32
#define HID 512
#define GROUPS 8            // blocks per batch
#define BLK_THREADS 512     // 8 waves (R20 best structure)
#define NBLOCKS 256
#define SLOT_DW (BATCH * GROUPS * 64)  // dwords per parity slot (16384 = 64 KB)

typedef _Float16 h2_t __attribute__((ext_vector_type(2)));
typedef uint32_t u32x8 __attribute__((ext_vector_type(8)));

__device__ inline uint32_t pack_h2(float a, float b) {
  h2_t v;
  v.x = (_Float16)a;
  v.y = (_Float16)b;
  return __builtin_bit_cast(uint32_t, v);
}

__device__ inline float fdot2(uint32_t a, uint32_t b, float c) {
  return __builtin_amdgcn_fdot2(__builtin_bit_cast(h2_t, a),
                                __builtin_bit_cast(h2_t, b), c, false);
}

__device__ inline uint64_t uni64(const void* p) {
  uint32_t lo = __builtin_amdgcn_readfirstlane((uint32_t)(uintptr_t)p);
  uint32_t hi = __builtin_amdgcn_readfirstlane((uint32_t)((uintptr_t)p >> 32));
  return ((uint64_t)hi << 32) | lo;
}

__device__ inline void kinv() {
  asm volatile("s_dcache_inv" ::: "memory");
}

// R11's fused poll+fetch (transport of every best round): 8 scalar loads
// back-to-back, ONE lgkmcnt(0) — 36 useful dwords (32 data + 4 in-line tags).
__device__ inline void sload_rec(uint64_t p, u32x8* d0, u32x8* d1,
                                 u32x8* d2, u32x8* d3,
                                 uint32_t* t0, uint32_t* t1,
                                 uint32_t* t2, uint32_t* t3) {
  asm volatile("s_load_dwordx8 %0, %8, 0x0\n\t"
               "s_load_dword %4, %8, 0x20\n\t"
               "s_load_dwordx8 %1, %8, 0x40\n\t"
               "s_load_dword %5, %8, 0x60\n\t"
               "s_load_dwordx8 %2, %8, 0x80\n\t"
               "s_load_dword %6, %8, 0xa0\n\t"
               "s_load_dwordx8 %3, %8, 0xc0\n\t"
               "s_load_dword %7, %8, 0xe0\n\t"
               "s_waitcnt lgkmcnt(0)"
               : "=&s"(*d0), "=&s"(*d1), "=&s"(*d2), "=&s"(*d3),
                 "=&s"(*t0), "=&s"(*t1), "=&s"(*t2), "=&s"(*t3)
               : "s"(p) : "memory");
}

__device__ inline float sigf(float x) { return 1.0f / (1.0f + __expf(-x)); }
__device__ inline float tanh_fast(float x) {
  float a = fabsf(x);
  float e = __expf(-2.0f * a);
  float r = (1.0f - e) / (1.0f + e);
  return copysignf(r, x);
}

// Round 22: DVFS heat. Twelve probes (transport, pollers, barriers, fan-in,
// ILP, sleep policy, tail order) all land at 14-16.7 ms — per-step cost is
// invariant in TIME. But identical dispatches within one session swing
// 14.5<->55 ms (3.9x) with identical per-step counters: the signature of
// CLOCK scaling, not of any instruction-level cost. This kernel is ~75%
// wait (VALUBusy 27%, occ 24%, HBM 0%) — the governor sees an idle chip and
// drops the core clock; the ~2150-cycle dependency chain then takes 3.3 µs
// at ~650 MHz == the measured floor. Fix: dense VALU FMA chains inside BOTH
// wait loops (32/iter in the poll, 16/iter in the arrive spin, asm-sunk so
// they aren't DCE'd). Cost on the chain: <=64 cy per poll iteration.
// Everything else is R20 byte-identical (+ R21's all-thread blin fix).
__global__ __launch_bounds__(BLK_THREADS)
void lstm_heat(const float* __restrict__ x0,
               const float* __restrict__ W_ih,
               const float* __restrict__ W_hh,
               const float* __restrict__ b_ih,
               const float* __restrict__ b_hh,
               const float* __restrict__ W_lin,
               const float* __restrict__ b_lin,
               float* __restrict__ y,
               uint32_t* __restrict__ h_ex,   // [2][BATCH][GROUPS][64]
               int* __restrict__ claim)       // [8][16] per-XCD claim ctrs
{
  __shared__ float x0_lds[T_STEPS];     // 16 KB
  __shared__ float ylds[T_STEPS];       // 16 KB
  __shared__ float gacc[2][256];        // parity-buffered gate accumulators
  __shared__ int arrive[2];             // parity arrival counters
  __shared__ int s_bg;

  const int tid = threadIdx.x;

  // ---- claim a (batch, group) slot on THIS block's physical XCD ----
  if (tid == 0) {
    uint32_t xcc;
    asm volatile("s_getreg_b32 %0, hwreg(HW_REG_XCC_ID)" : "=s"(xcc));
    xcc &= 7;
    int slot = atomicAdd(claim + xcc * 16, 1);   // one-time
    s_bg = (slot < 32) ? (int)(((4 * xcc + (slot >> 3)) << 3) | (slot & 7))
                       : -1;
  }
  __syncthreads();
  if (s_bg < 0) return;                  // surplus block
  const int b  = s_bg >> 3;              // batch (same XCD for all 8 groups)
  const int g  = s_bg & 7;               // group within batch
  const int u0 = g * 64;                 // first hidden unit owned
  const int wv = tid >> 6;               // wave 0..7
  const int cs = wv;                     // col-slice == producer group
  const int l  = tid & 63;

  // ---- one-time: W_hh slice -> packed f16x2 -> VGPRs ----
  uint32_t w[4][32];
#pragma unroll
  for (int a = 0; a < 4; ++a) {
    const int R = a * HID + u0 + l;                    // gate*512 + unit
    const float2* p = (const float2*)(W_hh + (size_t)R * HID + 64 * cs);
#pragma unroll
    for (int k = 0; k < 32; ++k) {
      float2 q = p[k];
      w[a][k] = pack_h2(q.x, q.y);
    }
  }
  // ---- one-time: x0 column, y partials, gacc, arrive ----
  for (int i = tid; i < T_STEPS; i += BLK_THREADS) {
    x0_lds[i] = x0[i * BATCH + b];
    ylds[i] = 0.f;
  }
  if (tid < 256) { gacc[0][tid] = 0.f; gacc[1][tid] = 0.f; }
  if (tid < 2) arrive[tid] = 0;

  // ---- activation-lane constants ----
  float c_state = 0.f;
  float wih_[4] = {0.f, 0.f, 0.f, 0.f}, bs_[4] = {0.f, 0.f, 0.f, 0.f};
  float wlin_u = 0.f;
  const float blin = b_lin[0];          // ALL threads (drain uses it; R21 fix)
  if (tid < 64) {
#pragma unroll
    for (int j = 0; j < 4; ++j) {
      int R = j * HID + u0 + tid;
      wih_[j] = W_ih[R];
      bs_[j] = b_ih[R] + b_hh[R];
    }
    wlin_u = W_lin[u0 + tid];
  }

  // ---- wave-uniform SGPR addresses (tagged-line record layout) ----
  uint32_t* hb = h_ex + (size_t)b * (GROUPS * 64);
  const uint64_t dpu[2] = { uni64(hb + 64 * cs),
                            uni64(hb + SLOT_DW + 64 * cs) };
  uint32_t* pub01[2] = { hb + 64 * g, hb + SLOT_DW + 64 * g };

  __syncthreads();

  float heat = 1.0f + (float)tid * 1e-7f;   // DVFS heater accumulator
  int dead = 0;
  for (int t = 0; t < T_STEPS; ++t) {
    const int sl = t & 1, ns = sl ^ 1;

    // ---- fused poll+fetch with VALU heat (keeps clocks at boost) ----
    u32x8 D0, D1, D2, D3;
    uint32_t tg0, tg1, tg2, tg3;
    {
      const uint32_t want = (uint32_t)t;
      int guard = 0;
      for (;;) {
        kinv();
        sload_rec(dpu[sl], &D0, &D1, &D2, &D3, &tg0, &tg1, &tg2, &tg3);
        if ((tg0 == want) & (tg1 == want) &
            (tg2 == want) & (tg3 == want)) break;
        if (dead || ++guard > (1 << 14)) { dead = 1; break; }  // anti-hang
        // 32-deep FMA chain (~64 cy): real VALU activity during the wait
#pragma unroll
        for (int hi = 0; hi < 32; ++hi)
          heat = __builtin_fmaf(heat, 1.0000001f, 1e-9f);
        asm volatile("" :: "v"(heat));   // live sink, no DCE
      }
    }

    // ---- matvec: 4 gate-rows x 64 cols per lane; 8 independent chains ----
    __builtin_amdgcn_s_setprio(1);
    float ae0 = 0.f, ao0 = 0.f, ae1 = 0.f, ao1 = 0.f;
    float ae2 = 0.f, ao2 = 0.f, ae3 = 0.f, ao3 = 0.f;
#pragma unroll
    for (int k = 0; k < 8; k += 2) {
      ae0 = fdot2(w[0][k], D0[k], ae0);      ao0 = fdot2(w[0][k + 1], D0[k + 1], ao0);
      ae1 = fdot2(w[1][k], D0[k], ae1);      ao1 = fdot2(w[1][k + 1], D0[k + 1], ao1);
      ae2 = fdot2(w[2][k], D0[k], ae2);      ao2 = fdot2(w[2][k + 1], D0[k + 1], ao2);
      ae3 = fdot2(w[3][k], D0[k], ae3);      ao3 = fdot2(w[3][k + 1], D0[k + 1], ao3);
      ae0 = fdot2(w[0][8 + k], D1[k], ae0);  ao0 = fdot2(w[0][9 + k], D1[k + 1], ao0);
      ae1 = fdot2(w[1][8 + k], D1[k], ae1);  ao1 = fdot2(w[1][9 + k], D1[k + 1], ao1);
      ae2 = fdot2(w[2][8 + k], D1[k], ae2);  ao2 = fdot2(w[2][9 + k], D1[k + 1], ao2);
      ae3 = fdot2(w[3][8 + k], D1[k], ae3);  ao3 = fdot2(w[3][9 + k], D1[k + 1], ao3);
      ae0 = fdot2(w[0][16 + k], D2[k], ae0); ao0 = fdot2(w[0][17 + k], D2[k + 1], ao0);
      ae1 = fdot2(w[1][16 + k], D2[k], ae1); ao1 = fdot2(w[1][17 + k], D2[k + 1], ao1);
      ae2 = fdot2(w[2][16 + k], D2[k], ae2); ao2 = fdot2(w[2][17 + k], D2[k + 1], ao2);
      ae3 = fdot2(w[3][16 + k], D2[k], ae3); ao3 = fdot2(w[3][17 + k], D2[k + 1], ao3);
      ae0 = fdot2(w[0][24 + k], D3[k], ae0); ao0 = fdot2(w[0][25 + k], D3[k + 1], ao0);
      ae1 = fdot2(w[1][24 + k], D3[k], ae1); ao1 = fdot2(w[1][25 + k], D3[k + 1], ao1);
      ae2 = fdot2(w[2][24 + k], D3[k], ae2); ao2 = fdot2(w[2][25 + k], D3[k + 1], ao2);
      ae3 = fdot2(w[3][24 + k], D3[k], ae3); ao3 = fdot2(w[3][25 + k], D3[k + 1], ao3);
    }
    atomicAdd(&gacc[sl][l],       ae0 + ao0);   // conflict-free across lanes
    atomicAdd(&gacc[sl][64 + l],  ae1 + ao1);
    atomicAdd(&gacc[sl][128 + l], ae2 + ao2);
    atomicAdd(&gacc[sl][192 + l], ae3 + ao3);
    asm volatile("" ::: "memory");       // adds ordered before the inc
    if (l == 0) atomicAdd(&arrive[sl], 1);
    __builtin_amdgcn_s_setprio(0);
    // waves 1-7 fall through to poll t+1 NOW (overlap wave 0's tail)

    // ---- activation + publish (wave 0 only; no block barrier) ----
    if (tid < 64) {
      {
        int guard = 0;
        while (((volatile int*)arrive)[sl] < 8) {   // LDS spin + VALU heat
          if (++guard > (1 << 18)) break;           // anti-hang
#pragma unroll
          for (int hi = 0; hi < 16; ++hi)
            heat = __builtin_fmaf(heat, 1.0000001f, 1e-9f);
          asm volatile("" :: "v"(heat));
        }
      }
      asm volatile("" ::: "memory");
      __builtin_amdgcn_s_setprio(1);
      arrive[sl] = 0;                    // reset for t+2 (tag chain gates)

      const float xv = x0_lds[t];
      float gi = gacc[sl][tid]       + xv * wih_[0] + bs_[0];
      float gf = gacc[sl][tid + 64]  + xv * wih_[1] + bs_[1];
      float gg = gacc[sl][tid + 128] + xv * wih_[2] + bs_[2];
      float go = gacc[sl][tid + 192] + xv * wih_[3] + bs_[3];
      float si = sigf(gi), sf = sigf(gf), tg_ = tanh_fast(gg), so = sigf(go);
      c_state = sf * c_state + si * tg_;
      float h = so * tanh_fast(c_state);

      // publish: 36-lane predicated store of 4 self-certifying lines
      float hn = __shfl_down(h, 1, 64);
      uint32_t val = 0;
      int doff = 0;
      bool act = false;
      if ((tid & 1) == 0) {
        int j = tid >> 1;
        val = pack_h2(h, hn);
        doff = ((j >> 3) << 4) + (j & 7);
        act = true;
      } else if (tid < 8) {
        int L = (tid - 1) >> 1;
        val = (uint32_t)(t + 1);
        doff = (L << 4) + 8;
        act = true;
      }
      if (act) pub01[ns][doff] = val;

      // recycle gacc[sl] for t+2
      gacc[sl][tid] = 0.f;
      gacc[sl][tid + 64] = 0.f;
      gacc[sl][tid + 128] = 0.f;
      gacc[sl][tid + 192] = 0.f;

      // y partial (off critical path)
      float p = wlin_u * h;
#pragma unroll
      for (int m = 32; m >= 1; m >>= 1) p += __shfl_xor(p, m, 64);
      if (tid == 0) ylds[t] = p;
      __builtin_amdgcn_s_setprio(0);
    }
  }

  // ---- drain: block partials -> global y (g==0 adds bias + residual) ----
  __syncthreads();
  for (int i = tid; i < T_STEPS; i += BLK_THREADS) {
    float val = ylds[i];
    if (g == 0) val += blin + x0_lds[i];
    unsafeAtomicAdd(&y[i * BATCH + b], val);
  }
}

extern "C" void kernel_launch(void* const* d_in, const int* in_sizes, int n_in,
                              void* d_out, int out_size, void* d_ws, size_t ws_size,
                              hipStream_t stream) {
  const float* x0    = (const float*)d_in[0];
  const float* W_ih  = (const float*)d_in[1];
  const float* W_hh  = (const float*)d_in[2];
  const float* b_ih  = (const float*)d_in[3];
  const float* b_hh  = (const float*)d_in[4];
  const float* W_lin = (const float*)d_in[5];
  const float* b_lin = (const float*)d_in[6];
  float* y = (float*)d_out;

  uint32_t* h_ex = (uint32_t*)d_ws;                    // 2 x 64 KB slots
  int* claim     = (int*)(h_ex + 2 * SLOT_DW);         // 512 B
  const size_t init_bytes = (size_t)2 * SLOT_DW * sizeof(uint32_t)
                            + 8 * 16 * sizeof(int);

  // memset 0: slot-0 tags = 0 with h = 0 (== "h_0 available"), claim = 0
  (void)hipMemsetAsync(d_ws, 0, init_bytes, stream);
  (void)hipMemsetAsync(d_out, 0, (size_t)out_size * sizeof(float), stream);

  hipLaunchKernelGGL(lstm_heat, dim3(NBLOCKS), dim3(BLK_THREADS), 0, stream,
                     x0, W_ih, W_hh, b_ih, b_hh, W_lin, b_lin, y, h_ex, claim);
}